// Round 4
// baseline (480.392 us; speedup 1.0000x reference)
//
#include <hip/hip_runtime.h>
#include <hip/hip_fp16.h>
#include <math.h>

// Graph TransformerConv ×2 on MI355X. N=100k, E=800k, D=64, H=4, C=64.
//
// R17: k_gemm - stores OUT of the load FIFO + explicit load pipelining.
//  - R16 post-mortem: occupancy 66% but dur 104us; VGPR=32 (compiler
//    register-minimized -> serial load chains) and each mat's flush stores
//    sat in the vmcnt FIFO ahead of the next mat's weight loads -> every
//    weight wait transitively waited for store acks (FIFO semantics).
//  - Now: wave = 16 nodes x channel-HALF (128 ch of Q/K/V, 32 of S).
//    All 4 mats staged into a wave-private LDS patch [16 nodes][528 B]
//    (Q@0|K@128|V@256|S@384, 16-B pad; bank-floor for all access shapes).
//    Global stores happen ONLY at the end: 8 insts x 8 nodes x 128-B full
//    aligned lines (stride 1024, no partial-line RMW). Zero barriers.
//  - Weight loads: explicit depth-1 prefetch (named next-iter regs, full
//    unroll) so chains pipeline; ~54 VGPR under launch_bounds(128,8) cap.
//  - 128-thd blocks, LDS 16896 B -> 9 blk/CU = 18 waves/CU, 12500 waves.
//  - NB[node][1024]: Q i8 @0 | K i8 @256 | V fp8 @512 | S f32 @768.
// CSR: hist stores rank[e] (one atomic pass, fused into layer-1 GEMM
// dispatch); scatter atomic-free. 8 dispatches. Attn unchanged.
// Workspace ~125 MB (guarded).

typedef __attribute__((ext_vector_type(8))) short bf16x8;
typedef __attribute__((ext_vector_type(4))) float f32x4;
typedef __attribute__((ext_vector_type(2))) float f32x2;

#define QKSCALE 32.0f
#define C_EXP2 1.760325e-4f   // log2e / (32*32*8)

__device__ inline unsigned short f2bf(float f) {
    unsigned int u = __float_as_uint(f);
    u = (u + 0x7fffu + ((u >> 16) & 1u)) >> 16;
    return (unsigned short)u;
}

#if __has_builtin(__builtin_amdgcn_cvt_pk_fp8_f32) && __has_builtin(__builtin_amdgcn_cvt_pk_f32_fp8)
#define HW_FP8 1
#endif

#ifndef HW_FP8
__device__ inline unsigned int fp8_enc1(float f) {
    unsigned int u = __float_as_uint(f);
    unsigned int s = (u >> 24) & 0x80u;
    float a = fabsf(f);
    if (a >= 448.f) return s | 0x7Eu;
    if (a < 0.015625f) return s;
    unsigned int ua = __float_as_uint(a);
    unsigned int r = ua + 0x7FFFFu + ((ua >> 20) & 1u);
    int e = (int)((r >> 23) & 255u) - 120;
    unsigned int m = (r >> 20) & 7u;
    if (e < 1) return s;
    if (e > 15) return s | 0x7Eu;
    return s | (unsigned int)((e << 3) | m);
}
__device__ inline float fp8_dec1(unsigned int b) {
    unsigned int e = (b >> 3) & 15u, m = b & 7u;
    float v;
    if (e) v = __uint_as_float(((e + 120u) << 23) | (m << 20));
    else   v = (float)m * 0.001953125f;
    return (b & 0x80u) ? -v : v;
}
#endif

__device__ inline unsigned int fp8x4_pack(float f0, float f1, float f2, float f3) {
#ifdef HW_FP8
    int pk = __builtin_amdgcn_cvt_pk_fp8_f32(f0, f1, 0, false);
    pk = __builtin_amdgcn_cvt_pk_fp8_f32(f2, f3, pk, true);
    return (unsigned int)pk;
#else
    return fp8_enc1(f0) | (fp8_enc1(f1) << 8) | (fp8_enc1(f2) << 16) | (fp8_enc1(f3) << 24);
#endif
}

__device__ inline float4 fp8x4_unpack(unsigned int k) {
#ifdef HW_FP8
    f32x2 lo = __builtin_amdgcn_cvt_pk_f32_fp8((int)k, false);
    f32x2 hi = __builtin_amdgcn_cvt_pk_f32_fp8((int)k, true);
    return make_float4(lo[0], lo[1], hi[0], hi[1]);
#else
    return make_float4(fp8_dec1(k & 255u), fp8_dec1((k >> 8) & 255u),
                       fp8_dec1((k >> 16) & 255u), fp8_dec1(k >> 24));
#endif
}

__device__ inline unsigned int i8x4_pack(float f0, float f1, float f2, float f3) {
    int a = (int)rintf(f0 * QKSCALE); a = a < -127 ? -127 : (a > 127 ? 127 : a);
    int b = (int)rintf(f1 * QKSCALE); b = b < -127 ? -127 : (b > 127 ? 127 : b);
    int c = (int)rintf(f2 * QKSCALE); c = c < -127 ? -127 : (c > 127 ? 127 : c);
    int d = (int)rintf(f3 * QKSCALE); d = d < -127 ? -127 : (d > 127 ? 127 : d);
    return (unsigned int)((a & 255) | ((b & 255) << 8) | ((c & 255) << 16) | ((d & 255) << 24));
}

__device__ inline int sdot4(unsigned int a, unsigned int b, int c) {
#if __has_builtin(__builtin_amdgcn_sdot4)
    return __builtin_amdgcn_sdot4((int)a, (int)b, c, false);
#else
    int r = c;
#pragma unroll
    for (int i = 0; i < 4; ++i) {
        int ai = (int)(a << (24 - 8 * i)) >> 24;
        int bi = (int)(b << (24 - 8 * i)) >> 24;
        r += ai * bi;
    }
    return r;
#endif
}

// ---------------- setup: X cast + weight prep (both layers) + CSR zero -----
__global__ void k_setup(
    const float* __restrict__ x, unsigned short* __restrict__ Xb, int ncast4,
    const float* __restrict__ Wq1, const float* __restrict__ Wk1,
    const float* __restrict__ Wv1, const float* __restrict__ Ws1,
    const float* __restrict__ Wq2, const float* __restrict__ Wk2,
    const float* __restrict__ Wv2, const float* __restrict__ Ws2,
    unsigned short* __restrict__ Wt,
    int* __restrict__ counts, int N, int castBl)
{
    int b = blockIdx.x, tid = threadIdx.x;
    if (b < castBl) {
        int i = b * 256 + tid;
        if (i < ncast4) {
            float4 v = ((const float4*)x)[i];
            ushort4 o;
            o.x = f2bf(v.x); o.y = f2bf(v.y); o.z = f2bf(v.z); o.w = f2bf(v.w);
            ((ushort4*)Xb)[i] = o;
        }
    } else if (b < castBl + 416) {
        int j = (b - castBl) * 256 + tid;   // < 106496
        int layer = j / 53248;
        int r = j % 53248;
        if (r < 49152) {
            int m = r / 16384, w = r % 16384;
            int n = w / 64, k = w % 64;
            const float* W = (layer == 0)
                ? ((m == 0) ? Wq1 : (m == 1) ? Wk1 : Wv1)
                : ((m == 0) ? Wq2 : (m == 1) ? Wk2 : Wv2);
            Wt[layer * 53248 + m * 16384 + n * 64 + k] = f2bf(W[k * 256 + n]);
        } else {
            int w = r - 49152;
            int n = w / 64, k = w % 64;
            const float* W = (layer == 0) ? Ws1 : Ws2;
            Wt[layer * 53248 + 49152 + n * 64 + k] = f2bf(W[k * 64 + n]);
        }
    } else {
        int i = (b - castBl - 416) * 256 + tid;
        if (i < N) counts[i] = 0;
    }
}

// ---------------- CSR scan ----------------
#define SCAN_B 256
#define SCAN_CHUNK 2048
__global__ void k_scan1(const int* __restrict__ counts, int n,
                        int* __restrict__ offs, int* __restrict__ bsums) {
    __shared__ int lds[SCAN_B];
    int b = blockIdx.x, tid = threadIdx.x;
    int base = b * SCAN_CHUNK + tid * 8;
    int v[8]; int s = 0;
#pragma unroll
    for (int i = 0; i < 8; ++i) { int idx = base + i; int c = (idx < n) ? counts[idx] : 0; v[i] = s; s += c; }
    lds[tid] = s;
    for (int off = 1; off < SCAN_B; off <<= 1) {
        __syncthreads();
        int x = (tid >= off) ? lds[tid - off] : 0;
        __syncthreads();
        lds[tid] += x;
    }
    __syncthreads();
    int texcl = lds[tid] - s;
#pragma unroll
    for (int i = 0; i < 8; ++i) { int idx = base + i; if (idx < n) offs[idx] = texcl + v[i]; }
    if (tid == SCAN_B - 1) bsums[b] = lds[tid];
}

__global__ void k_scan2(int* bsums, int nb) {
    __shared__ int lds[256];
    int t = threadIdx.x;
    if (nb > 256) {
        if (t == 0) { int s = 0; for (int i = 0; i < nb; ++i) { int c = bsums[i]; bsums[i] = s; s += c; } }
        return;
    }
    int v = (t < nb) ? bsums[t] : 0;
    lds[t] = v;
    for (int off = 1; off < 256; off <<= 1) {
        __syncthreads();
        int x = (t >= off) ? lds[t - off] : 0;
        __syncthreads();
        lds[t] += x;
    }
    __syncthreads();
    if (t < nb) bsums[t] = lds[t] - v;   // exclusive
}

// atomic-free scatter using per-edge rank from the hist pass
__global__ void k_scatter(const int* __restrict__ src, const int* __restrict__ dst, int E,
                          const int* __restrict__ offs, const int* __restrict__ bsums,
                          const int* __restrict__ rank, int* __restrict__ csr_src) {
    int e = blockIdx.x * 256 + threadIdx.x;
    if (e < E) {
        int d = dst[e];
        csr_src[offs[d] + bsums[d >> 11] + rank[e]] = src[e];
    }
}

// ---------------- fused GEMM (+hist blocks) --------------------------------
// 128-thd block = 16 nodes. Wave h (0/1) computes channel-half h: Q/K/V
// ctiles h*8..h*8+7 (128 ch) and S ctiles 2h,2h+1 (32 ch). All results
// accumulate in a wave-private patch [16 nodes][528 B] (Q@0 K@128 V@256
// S@384, +16 pad). Weight loads use explicit depth-1 prefetch. GLOBAL
// STORES ONLY AT THE END: per mat 2 insts x 8 nodes x 128-B full lines
// -> the vmcnt FIFO holds only loads during the whole compute phase.
#define PROW 528
__global__ __launch_bounds__(128, 8) void k_gemm(
    const unsigned short* __restrict__ Xb, int nrows,
    const unsigned short* __restrict__ WtL,
    const float* __restrict__ bqp, const float* __restrict__ bkp,
    const float* __restrict__ bvp, const float* __restrict__ bsp,
    unsigned char* __restrict__ NB,
    const int* __restrict__ dstp, int histE,
    int* __restrict__ counts, int* __restrict__ rank, int gemmBl)
{
    __shared__ unsigned char st[2][16 * PROW];   // 16896 B -> 9 blk/CU
    int tid = threadIdx.x;
    if (blockIdx.x >= gemmBl) {                  // ---- hist blocks ----
        int e = (blockIdx.x - gemmBl) * 128 + tid;
        if (e < histE) rank[e] = atomicAdd(&counts[dstp[e]], 1);
        return;
    }
    int h = tid >> 6, lane = tid & 63;
    int quad = lane >> 4, n16 = lane & 15;
    int r0 = blockIdx.x * 16;
    unsigned char* wst = st[h];

    // A fragments for the block's 16 nodes (same for both waves)
    bf16x8 a0, a1;
    {
        int node = r0 + n16;
        int nodec = (node < nrows) ? node : (nrows - 1);
        a0 = *(const bf16x8*)(Xb + (size_t)nodec * 64 + quad * 8);
        a1 = *(const bf16x8*)(Xb + (size_t)nodec * 64 + 32 + quad * 8);
    }

    // one Q/K/V mat half: 8 ctiles, depth-1 prefetched weight pipeline
    auto do_qkv = [&](const unsigned short* W, const float* bp,
                      int poff, bool isInt8) {
        int cg = h * 8;
        const unsigned short* Wp = W + (cg * 16 + n16) * 64 + quad * 8;
        bf16x8 w0 = *(const bf16x8*)(Wp);
        bf16x8 w1 = *(const bf16x8*)(Wp + 32);
        float4 cb = *(const float4*)(bp + cg * 16 + quad * 4);
#pragma unroll
        for (int c = 0; c < 8; ++c) {
            bf16x8 nw0 = w0, nw1 = w1; float4 ncb = cb;
            if (c < 7) {
                const unsigned short* Wn = W + ((cg + c + 1) * 16 + n16) * 64 + quad * 8;
                nw0 = *(const bf16x8*)(Wn);
                nw1 = *(const bf16x8*)(Wn + 32);
                ncb = *(const float4*)(bp + (cg + c + 1) * 16 + quad * 4);
            }
            f32x4 acc = {0.f, 0.f, 0.f, 0.f};
            acc = __builtin_amdgcn_mfma_f32_16x16x32_bf16(w0, a0, acc, 0, 0, 0);
            acc = __builtin_amdgcn_mfma_f32_16x16x32_bf16(w1, a1, acc, 0, 0, 0);
            float f0 = acc[0] + cb.x, f1 = acc[1] + cb.y;
            float f2 = acc[2] + cb.z, f3 = acc[3] + cb.w;
            unsigned int pk = isInt8 ? i8x4_pack(f0, f1, f2, f3)
                                     : fp8x4_pack(f0, f1, f2, f3);
            *(unsigned int*)(wst + n16 * PROW + poff + c * 16 + quad * 4) = pk;
            w0 = nw0; w1 = nw1; cb = ncb;
        }
    };

    const unsigned short* Wq = WtL;
    const unsigned short* Wk = WtL + 16384;
    const unsigned short* Wv = WtL + 32768;
    const unsigned short* Ws = WtL + 49152;

    do_qkv(Wq, bqp, 0, true);       // Q int8 -> patch [0,128)
    do_qkv(Wk, bkp, 128, true);     // K int8 -> patch [128,256)
    do_qkv(Wv, bvp, 256, false);    // V fp8  -> patch [256,384)

    // ---- S (fp32 skip): ctiles 2h, 2h+1 -> patch [384,512) ----
#pragma unroll
    for (int cl = 0; cl < 2; ++cl) {
        int c = 2 * h + cl;
        int roff = (c * 16 + n16) * 64 + quad * 8;
        bf16x8 s0 = *(const bf16x8*)(Ws + roff);
        bf16x8 s1 = *(const bf16x8*)(Ws + roff + 32);
        float4 cs = *(const float4*)(bsp + c * 16 + quad * 4);
        f32x4 acc = {0.f, 0.f, 0.f, 0.f};
        acc = __builtin_amdgcn_mfma_f32_16x16x32_bf16(s0, a0, acc, 0, 0, 0);
        acc = __builtin_amdgcn_mfma_f32_16x16x32_bf16(s1, a1, acc, 0, 0, 0);
        *(float4*)(wst + n16 * PROW + 384 + cl * 64 + quad * 16) =
            make_float4(acc[0] + cs.x, acc[1] + cs.y, acc[2] + cs.z, acc[3] + cs.w);
    }

    // ---- flush: ONLY global stores in the kernel; full 128-B lines ----
#pragma unroll
    for (int m = 0; m < 4; ++m) {
#pragma unroll
        for (int it = 0; it < 2; ++it) {
            int nl = it * 8 + (lane >> 3);
            uint4 v = *(const uint4*)(wst + nl * PROW + m * 128 + (lane & 7) * 16);
            int nd = r0 + nl;
            if (nd < nrows)
                *(uint4*)(NB + (size_t)nd * 1024 + m * 256 + h * 128 + (lane & 7) * 16) = v;
        }
    }
}

// ---------------- Attention: split-wave edge pairs, int8 dot ---------------
__global__ __launch_bounds__(256) void k_attn(
    const unsigned char* __restrict__ NB,
    const int* __restrict__ offs, const int* __restrict__ bsums,
    const int* __restrict__ csr_src,
    float* __restrict__ out, unsigned short* __restrict__ Xb,
    int n, int Etot, int mode)
{
    int node = blockIdx.x * 4 + (threadIdx.x >> 6);
    if (node >= n) return;
    int lane = threadIdx.x & 63;
    int sl = lane & 31;
    int half = lane >> 5;
    uint2 q8 = *(const uint2*)(NB + (size_t)node * 1024 + sl * 8);
    int beg = offs[node] + bsums[node >> 11];
    int end = (node + 1 < n) ? (offs[node + 1] + bsums[(node + 1) >> 11]) : Etot;
    float l = 0.f;
    float acc[8];
#pragma unroll
    for (int i = 0; i < 8; ++i) acc[i] = 0.f;
    for (int base = beg; base < end; base += 8) {
        int cnt = end - base; if (cnt > 8) cnt = 8;
        int my = (lane < cnt) ? csr_src[base + lane] : 0;
        uint2 kk[4], vv[4];
#pragma unroll
        for (int p = 0; p < 4; ++p) {
            int idx = __shfl(my, 2 * p + half);
            const unsigned char* row = NB + (size_t)idx * 1024 + 256 + sl * 8;
            kk[p] = *(const uint2*)(row);
            vv[p] = *(const uint2*)(row + 256);
        }
#pragma unroll
        for (int p = 0; p < 4; ++p) {
            int d = sdot4(kk[p].x, q8.x, 0);
            d = sdot4(kk[p].y, q8.y, d);
            d += __shfl_xor(d, 1); d += __shfl_xor(d, 2); d += __shfl_xor(d, 4);
            float w = __builtin_exp2f((float)d * C_EXP2);
            w = (2 * p + half < cnt) ? w : 0.f;
            l += w;
            float4 va = fp8x4_unpack(vv[p].x);
            float4 vb = fp8x4_unpack(vv[p].y);
            acc[0] += va.x * w; acc[1] += va.y * w;
            acc[2] += va.z * w; acc[3] += va.w * w;
            acc[4] += vb.x * w; acc[5] += vb.y * w;
            acc[6] += vb.z * w; acc[7] += vb.w * w;
        }
    }
    l += __shfl_xor(l, 32);
#pragma unroll
    for (int i = 0; i < 8; ++i) acc[i] += __shfl_xor(acc[i], 32);
    float inv = 1.f / (l + 1e-16f);
#pragma unroll
    for (int i = 0; i < 8; ++i) acc[i] *= inv;
#pragma unroll
    for (int i = 0; i < 8; ++i) {
        acc[i] += __shfl_xor(acc[i], 8);
        acc[i] += __shfl_xor(acc[i], 16);
        acc[i] *= 0.25f;
    }
    if (lane < 8) {
        const float* Srow = (const float*)(NB + (size_t)node * 1024 + 768);
        float4 s0 = *(const float4*)(Srow + lane * 8);
        float4 s1 = *(const float4*)(Srow + lane * 8 + 4);
        float r0 = acc[0] + s0.x, r1 = acc[1] + s0.y;
        float r2 = acc[2] + s0.z, r3 = acc[3] + s0.w;
        float r4 = acc[4] + s1.x, r5 = acc[5] + s1.y;
        float r6 = acc[6] + s1.z, r7 = acc[7] + s1.w;
        if (mode == 1) {
            r0 = fmaxf(r0, 0.f); r1 = fmaxf(r1, 0.f);
            r2 = fmaxf(r2, 0.f); r3 = fmaxf(r3, 0.f);
            r4 = fmaxf(r4, 0.f); r5 = fmaxf(r5, 0.f);
            r6 = fmaxf(r6, 0.f); r7 = fmaxf(r7, 0.f);
            uint4 o;
            o.x = (unsigned int)f2bf(r0) | ((unsigned int)f2bf(r1) << 16);
            o.y = (unsigned int)f2bf(r2) | ((unsigned int)f2bf(r3) << 16);
            o.z = (unsigned int)f2bf(r4) | ((unsigned int)f2bf(r5) << 16);
            o.w = (unsigned int)f2bf(r6) | ((unsigned int)f2bf(r7) << 16);
            *(uint4*)(Xb + (size_t)node * 64 + lane * 8) = o;
        } else {
            *(float4*)(out + (size_t)node * 64 + lane * 8) = make_float4(r0, r1, r2, r3);
            *(float4*)(out + (size_t)node * 64 + lane * 8 + 4) = make_float4(r4, r5, r6, r7);
        }
    }
}

extern "C" void kernel_launch(void* const* d_in, const int* in_sizes, int n_in,
                              void* d_out, int out_size, void* d_ws, size_t ws_size,
                              hipStream_t stream)
{
    const float* x  = (const float*)d_in[0];
    const int*   ei = (const int*)d_in[1];
    int N = in_sizes[0] / 64;
    int E = in_sizes[1] / 2;
    const int* srcp = ei;
    const int* dstp = ei + E;
    const float* Wq1 = (const float*)d_in[2],  *bq1 = (const float*)d_in[3];
    const float* Wk1 = (const float*)d_in[4],  *bk1 = (const float*)d_in[5];
    const float* Wv1 = (const float*)d_in[6],  *bv1 = (const float*)d_in[7];
    const float* Ws1 = (const float*)d_in[8],  *bs1 = (const float*)d_in[9];
    const float* Wq2 = (const float*)d_in[10], *bq2 = (const float*)d_in[11];
    const float* Wk2 = (const float*)d_in[12], *bk2 = (const float*)d_in[13];
    const float* Wv2 = (const float*)d_in[14], *bv2 = (const float*)d_in[15];
    const float* Ws2 = (const float*)d_in[16], *bs2 = (const float*)d_in[17];
    float* out = (float*)d_out;

    // workspace layout (~125 MB)
    char* ws = (char*)d_ws;
    size_t off = 0;
    auto alloc = [&](size_t bytes) -> void* {
        void* p = ws + off;
        off = (off + bytes + 255) & ~(size_t)255;
        return p;
    };
    unsigned short* Xb = (unsigned short*)alloc((size_t)N * 64 * 2);
    unsigned char* NB  = (unsigned char*)alloc(((size_t)N + 64) * 1024);
    unsigned short* Wt = (unsigned short*)alloc(2 * 53248 * 2);
    int* counts = (int*)alloc((size_t)N * 4);
    int* rank   = (int*)alloc((size_t)E * 4);
    int* offs   = (int*)alloc((size_t)N * 4);
    int* bsums  = (int*)alloc(1024 * 4);
    int* csr    = (int*)alloc((size_t)E * 4);
    (void)n_in; (void)out_size;
    if (off > ws_size) return;  // diagnostic: too-small ws -> zeros, not a fault

    int ebl = (E + 255) / 256;
    int nb_scan = (N + SCAN_CHUNK - 1) / SCAN_CHUNK;
    int gemm_bl = (N + 15) / 16;              // 128-thd blocks, 16 nodes each
    int hist_bl = (E + 127) / 128;
    int attn_bl = (N + 3) / 4;
    int ncast4 = N * 16;
    int castBl = (ncast4 + 255) / 256;
    int zeroBl = (N + 255) / 256;

    // 1. setup: cast X, prep weights, zero counts
    k_setup<<<castBl + 416 + zeroBl, 256, 0, stream>>>(
        x, Xb, ncast4, Wq1, Wk1, Wv1, Ws1, Wq2, Wk2, Wv2, Ws2, Wt, counts, N, castBl);

    // 2. layer-1 GEMM + fused hist (independent block ranges)
    k_gemm<<<gemm_bl + hist_bl, 128, 0, stream>>>(
        Xb, N, Wt, bq1, bk1, bv1, bs1, NB,
        dstp, E, counts, rank, gemm_bl);

    // 3-5. CSR: scan, scan2, atomic-free scatter
    k_scan1<<<nb_scan, SCAN_B, 0, stream>>>(counts, N, offs, bsums);
    k_scan2<<<1, 256, 0, stream>>>(bsums, nb_scan);
    k_scatter<<<ebl, 256, 0, stream>>>(srcp, dstp, E, offs, bsums, rank, csr);

    // 6. layer-1 attention (h1 -> Xb bf16)
    k_attn<<<attn_bl, 256, 0, stream>>>(NB, offs, bsums, csr, out, Xb, N, E, 1);

    // 7. layer-2 GEMM (no hist blocks)
    k_gemm<<<gemm_bl, 128, 0, stream>>>(
        Xb, N, Wt + 53248, bq2, bk2, bv2, bs2, NB,
        dstp, 0, counts, rank, gemm_bl);

    // 8. layer-2 attention
    k_attn<<<attn_bl, 256, 0, stream>>>(NB, offs, bsums, csr, out, Xb, N, E, 0);
}

// Round 5
// 366.598 us; speedup vs baseline: 1.3104x; 1.3104x over previous
//
#include <hip/hip_runtime.h>
#include <hip/hip_fp16.h>
#include <math.h>

// Graph TransformerConv ×2 on MI355X. N=100k, E=800k, D=64, H=4, C=64.
//
// R18: persistent-weight grid-stride k_gemm.
//  - Cross-round data (R13-R17): dur tracks weight-load chains per wave,
//    NOT occupancy (8->21 waves/CU changed nothing). Fix: each wave loads
//    its ch-quarter of Q/K/V/S ONCE into regs (26 b128 loads, 104 VGPR),
//    then grid-strides over ~3 node-tiles of 64. Inner tile body has ZERO
//    loads: 104 independent MFMAs + pack + LDS + stores.
//  - Biases staged to LDS once and used as MFMA C-IN (acc init = bias):
//    saves 52 VGPR + 4 VALU/ctile vs register-held biases.
//  - A-fragments depth-1 prefetched across tiles; prefetch loads precede
//    the tile's stores in the vmcnt FIFO, so the next-tile wait (counted)
//    never waits on store completion.
//  - Staging/flush = R13's proven-clean wave-private shape (FETCH 8.8 MB,
//    WRITE 128 MB): 64x68-B patch, 4x 1-KB dwordx4 stores per mat.
//  - __launch_bounds__(256,2); 512 gemm blocks (2/CU), zero barriers in
//    the loop (one initial __syncthreads for bias visibility).
//  - NB[node][1024]: Q i8 @0 | K i8 @256 | V fp8 @512 | S f32 @768.
// CSR: hist stores rank[e] (one atomic pass, fused into layer-1 GEMM
// dispatch); scatter atomic-free. 8 dispatches. Attn unchanged.
// Workspace ~125 MB (guarded).

typedef __attribute__((ext_vector_type(8))) short bf16x8;
typedef __attribute__((ext_vector_type(4))) float f32x4;
typedef __attribute__((ext_vector_type(2))) float f32x2;

#define QKSCALE 32.0f
#define C_EXP2 1.760325e-4f   // log2e / (32*32*8)

__device__ inline unsigned short f2bf(float f) {
    unsigned int u = __float_as_uint(f);
    u = (u + 0x7fffu + ((u >> 16) & 1u)) >> 16;
    return (unsigned short)u;
}

#if __has_builtin(__builtin_amdgcn_cvt_pk_fp8_f32) && __has_builtin(__builtin_amdgcn_cvt_pk_f32_fp8)
#define HW_FP8 1
#endif

#ifndef HW_FP8
__device__ inline unsigned int fp8_enc1(float f) {
    unsigned int u = __float_as_uint(f);
    unsigned int s = (u >> 24) & 0x80u;
    float a = fabsf(f);
    if (a >= 448.f) return s | 0x7Eu;
    if (a < 0.015625f) return s;
    unsigned int ua = __float_as_uint(a);
    unsigned int r = ua + 0x7FFFFu + ((ua >> 20) & 1u);
    int e = (int)((r >> 23) & 255u) - 120;
    unsigned int m = (r >> 20) & 7u;
    if (e < 1) return s;
    if (e > 15) return s | 0x7Eu;
    return s | (unsigned int)((e << 3) | m);
}
__device__ inline float fp8_dec1(unsigned int b) {
    unsigned int e = (b >> 3) & 15u, m = b & 7u;
    float v;
    if (e) v = __uint_as_float(((e + 120u) << 23) | (m << 20));
    else   v = (float)m * 0.001953125f;
    return (b & 0x80u) ? -v : v;
}
#endif

__device__ inline unsigned int fp8x4_pack(float f0, float f1, float f2, float f3) {
#ifdef HW_FP8
    int pk = __builtin_amdgcn_cvt_pk_fp8_f32(f0, f1, 0, false);
    pk = __builtin_amdgcn_cvt_pk_fp8_f32(f2, f3, pk, true);
    return (unsigned int)pk;
#else
    return fp8_enc1(f0) | (fp8_enc1(f1) << 8) | (fp8_enc1(f2) << 16) | (fp8_enc1(f3) << 24);
#endif
}

__device__ inline float4 fp8x4_unpack(unsigned int k) {
#ifdef HW_FP8
    f32x2 lo = __builtin_amdgcn_cvt_pk_f32_fp8((int)k, false);
    f32x2 hi = __builtin_amdgcn_cvt_pk_f32_fp8((int)k, true);
    return make_float4(lo[0], lo[1], hi[0], hi[1]);
#else
    return make_float4(fp8_dec1(k & 255u), fp8_dec1((k >> 8) & 255u),
                       fp8_dec1((k >> 16) & 255u), fp8_dec1(k >> 24));
#endif
}

__device__ inline unsigned int i8x4_pack(float f0, float f1, float f2, float f3) {
    int a = (int)rintf(f0 * QKSCALE); a = a < -127 ? -127 : (a > 127 ? 127 : a);
    int b = (int)rintf(f1 * QKSCALE); b = b < -127 ? -127 : (b > 127 ? 127 : b);
    int c = (int)rintf(f2 * QKSCALE); c = c < -127 ? -127 : (c > 127 ? 127 : c);
    int d = (int)rintf(f3 * QKSCALE); d = d < -127 ? -127 : (d > 127 ? 127 : d);
    return (unsigned int)((a & 255) | ((b & 255) << 8) | ((c & 255) << 16) | ((d & 255) << 24));
}

__device__ inline int sdot4(unsigned int a, unsigned int b, int c) {
#if __has_builtin(__builtin_amdgcn_sdot4)
    return __builtin_amdgcn_sdot4((int)a, (int)b, c, false);
#else
    int r = c;
#pragma unroll
    for (int i = 0; i < 4; ++i) {
        int ai = (int)(a << (24 - 8 * i)) >> 24;
        int bi = (int)(b << (24 - 8 * i)) >> 24;
        r += ai * bi;
    }
    return r;
#endif
}

// ---------------- setup: X cast + weight prep (both layers) + CSR zero -----
__global__ void k_setup(
    const float* __restrict__ x, unsigned short* __restrict__ Xb, int ncast4,
    const float* __restrict__ Wq1, const float* __restrict__ Wk1,
    const float* __restrict__ Wv1, const float* __restrict__ Ws1,
    const float* __restrict__ Wq2, const float* __restrict__ Wk2,
    const float* __restrict__ Wv2, const float* __restrict__ Ws2,
    unsigned short* __restrict__ Wt,
    int* __restrict__ counts, int N, int castBl)
{
    int b = blockIdx.x, tid = threadIdx.x;
    if (b < castBl) {
        int i = b * 256 + tid;
        if (i < ncast4) {
            float4 v = ((const float4*)x)[i];
            ushort4 o;
            o.x = f2bf(v.x); o.y = f2bf(v.y); o.z = f2bf(v.z); o.w = f2bf(v.w);
            ((ushort4*)Xb)[i] = o;
        }
    } else if (b < castBl + 416) {
        int j = (b - castBl) * 256 + tid;   // < 106496
        int layer = j / 53248;
        int r = j % 53248;
        if (r < 49152) {
            int m = r / 16384, w = r % 16384;
            int n = w / 64, k = w % 64;
            const float* W = (layer == 0)
                ? ((m == 0) ? Wq1 : (m == 1) ? Wk1 : Wv1)
                : ((m == 0) ? Wq2 : (m == 1) ? Wk2 : Wv2);
            Wt[layer * 53248 + m * 16384 + n * 64 + k] = f2bf(W[k * 256 + n]);
        } else {
            int w = r - 49152;
            int n = w / 64, k = w % 64;
            const float* W = (layer == 0) ? Ws1 : Ws2;
            Wt[layer * 53248 + 49152 + n * 64 + k] = f2bf(W[k * 64 + n]);
        }
    } else {
        int i = (b - castBl - 416) * 256 + tid;
        if (i < N) counts[i] = 0;
    }
}

// ---------------- CSR scan ----------------
#define SCAN_B 256
#define SCAN_CHUNK 2048
__global__ void k_scan1(const int* __restrict__ counts, int n,
                        int* __restrict__ offs, int* __restrict__ bsums) {
    __shared__ int lds[SCAN_B];
    int b = blockIdx.x, tid = threadIdx.x;
    int base = b * SCAN_CHUNK + tid * 8;
    int v[8]; int s = 0;
#pragma unroll
    for (int i = 0; i < 8; ++i) { int idx = base + i; int c = (idx < n) ? counts[idx] : 0; v[i] = s; s += c; }
    lds[tid] = s;
    for (int off = 1; off < SCAN_B; off <<= 1) {
        __syncthreads();
        int x = (tid >= off) ? lds[tid - off] : 0;
        __syncthreads();
        lds[tid] += x;
    }
    __syncthreads();
    int texcl = lds[tid] - s;
#pragma unroll
    for (int i = 0; i < 8; ++i) { int idx = base + i; if (idx < n) offs[idx] = texcl + v[i]; }
    if (tid == SCAN_B - 1) bsums[b] = lds[tid];
}

__global__ void k_scan2(int* bsums, int nb) {
    __shared__ int lds[256];
    int t = threadIdx.x;
    if (nb > 256) {
        if (t == 0) { int s = 0; for (int i = 0; i < nb; ++i) { int c = bsums[i]; bsums[i] = s; s += c; } }
        return;
    }
    int v = (t < nb) ? bsums[t] : 0;
    lds[t] = v;
    for (int off = 1; off < 256; off <<= 1) {
        __syncthreads();
        int x = (t >= off) ? lds[t - off] : 0;
        __syncthreads();
        lds[t] += x;
    }
    __syncthreads();
    if (t < nb) bsums[t] = lds[t] - v;   // exclusive
}

// atomic-free scatter using per-edge rank from the hist pass
__global__ void k_scatter(const int* __restrict__ src, const int* __restrict__ dst, int E,
                          const int* __restrict__ offs, const int* __restrict__ bsums,
                          const int* __restrict__ rank, int* __restrict__ csr_src) {
    int e = blockIdx.x * 256 + threadIdx.x;
    if (e < E) {
        int d = dst[e];
        csr_src[offs[d] + bsums[d >> 11] + rank[e]] = src[e];
    }
}

// ---------------- persistent fused GEMM (+hist blocks) ---------------------
// 512 blocks x 256 thd. Wave w = ch-quarter w. Weights for the quarter
// (Q/K/V: 8 bf16x8 each, S: 2) live in registers for the whole kernel.
// Grid-stride loop over 64-node tiles: prefetch A(t+1) -> compute 104
// MFAMs from registers (bias as C-in from LDS) -> pack -> wave-private
// LDS patch (64x68 B) -> 16x 1-KB dwordx4 stores. Zero barriers in loop.
#define GST 68
__global__ __launch_bounds__(256, 2) void k_gemm(
    const unsigned short* __restrict__ Xb, int nrows,
    const unsigned short* __restrict__ WtL,
    const float* __restrict__ bqp, const float* __restrict__ bkp,
    const float* __restrict__ bvp, const float* __restrict__ bsp,
    unsigned char* __restrict__ NB,
    const int* __restrict__ dstp, int histE,
    int* __restrict__ counts, int* __restrict__ rank, int gemmBl, int ntiles)
{
    __shared__ unsigned char st[4][64 * GST];   // 17408 B
    __shared__ float bias[832];                 // Q@0 K@256 V@512 S@768
    int tid = threadIdx.x;
    if (blockIdx.x >= gemmBl) {                  // ---- hist blocks ----
        int e = (blockIdx.x - gemmBl) * 256 + tid;
        if (e < histE) rank[e] = atomicAdd(&counts[dstp[e]], 1);
        return;
    }
    int qtr = tid >> 6, lane = tid & 63;
    int quad = lane >> 4, n16 = lane & 15;
    unsigned char* wst = st[qtr];

    // stage biases once (832 floats = 208 float4)
    if (tid < 208) {
        float4 b4;
        if (tid < 64)       b4 = ((const float4*)bqp)[tid];
        else if (tid < 128) b4 = ((const float4*)bkp)[tid - 64];
        else if (tid < 192) b4 = ((const float4*)bvp)[tid - 128];
        else                b4 = ((const float4*)bsp)[tid - 192];
        ((float4*)bias)[tid] = b4;
    }

    // ---- weights for this wave's quarter -> registers (once) ----
    const unsigned short* Wq = WtL;
    const unsigned short* Wk = WtL + 16384;
    const unsigned short* Wv = WtL + 32768;
    const unsigned short* Ws = WtL + 49152;
    bf16x8 fQ[8], fK[8], fV[8], fS[2];
#pragma unroll
    for (int c = 0; c < 4; ++c) {
        int roff = ((qtr * 4 + c) * 16 + n16) * 64 + quad * 8;
        fQ[2 * c]     = *(const bf16x8*)(Wq + roff);
        fQ[2 * c + 1] = *(const bf16x8*)(Wq + roff + 32);
        fK[2 * c]     = *(const bf16x8*)(Wk + roff);
        fK[2 * c + 1] = *(const bf16x8*)(Wk + roff + 32);
        fV[2 * c]     = *(const bf16x8*)(Wv + roff);
        fV[2 * c + 1] = *(const bf16x8*)(Wv + roff + 32);
    }
    {
        int roff = (qtr * 16 + n16) * 64 + quad * 8;
        fS[0] = *(const bf16x8*)(Ws + roff);
        fS[1] = *(const bf16x8*)(Ws + roff + 32);
    }
    __syncthreads();   // bias visibility (one-time drain, amortized)

    auto loadA = [&](int t, bf16x8 (&x0)[4], bf16x8 (&x1)[4]) {
        int r0 = t * 64;
#pragma unroll
        for (int g = 0; g < 4; ++g) {
            int node = r0 + g * 16 + n16;
            int nodec = (node < nrows) ? node : (nrows - 1);
            x0[g] = *(const bf16x8*)(Xb + (size_t)nodec * 64 + quad * 8);
            x1[g] = *(const bf16x8*)(Xb + (size_t)nodec * 64 + 32 + quad * 8);
        }
    };

    // one mat: 4 ctiles x 4 node groups, bias as C-in; then dense flush
    auto do_mat = [&](const bf16x8 (&fm)[8], int boff, int matoff, bool isInt8,
                      int r0, const bf16x8 (&x0)[4], const bf16x8 (&x1)[4]) {
#pragma unroll
        for (int c = 0; c < 4; ++c) {
            float4 cb = *(const float4*)(bias + boff + qtr * 64 + c * 16 + quad * 4);
#pragma unroll
            for (int g = 0; g < 4; ++g) {
                f32x4 acc = {cb.x, cb.y, cb.z, cb.w};
                acc = __builtin_amdgcn_mfma_f32_16x16x32_bf16(fm[2 * c],     x0[g], acc, 0, 0, 0);
                acc = __builtin_amdgcn_mfma_f32_16x16x32_bf16(fm[2 * c + 1], x1[g], acc, 0, 0, 0);
                unsigned int pk = isInt8 ? i8x4_pack(acc[0], acc[1], acc[2], acc[3])
                                         : fp8x4_pack(acc[0], acc[1], acc[2], acc[3]);
                *(unsigned int*)(wst + (g * 16 + n16) * GST + c * 16 + quad * 4) = pk;
            }
        }
#pragma unroll
        for (int it = 0; it < 4; ++it) {
            int row = it * 16 + (lane >> 2);
            uint4 v = *(const uint4*)(wst + row * GST + (lane & 3) * 16);
            int nd = r0 + row;
            if (nd < nrows)
                *(uint4*)(NB + (size_t)nd * 1024 + matoff + qtr * 64 + (lane & 3) * 16) = v;
        }
    };

    // ---- grid-stride tile loop with depth-1 A prefetch ----
    bf16x8 a0[4], a1[4], b0[4], b1[4];
    int t = blockIdx.x;
    if (t < ntiles) loadA(t, a0, a1);
    for (; t < ntiles; t += gemmBl) {
        int tn = t + gemmBl;
        if (tn < ntiles) loadA(tn, b0, b1);
        int r0 = t * 64;
        do_mat(fQ, 0,   0,   true,  r0, a0, a1);   // Q int8
        do_mat(fK, 256, 256, true,  r0, a0, a1);   // K int8
        do_mat(fV, 512, 512, false, r0, a0, a1);   // V fp8
        // S (fp32 skip): quarter = 16 ch, bias as C-in, direct f32 patch
        {
            float4 cs = *(const float4*)(bias + 768 + qtr * 16 + quad * 4);
#pragma unroll
            for (int g = 0; g < 4; ++g) {
                f32x4 acc = {cs.x, cs.y, cs.z, cs.w};
                acc = __builtin_amdgcn_mfma_f32_16x16x32_bf16(fS[0], a0[g], acc, 0, 0, 0);
                acc = __builtin_amdgcn_mfma_f32_16x16x32_bf16(fS[1], a1[g], acc, 0, 0, 0);
                *(float4*)(wst + (g * 16 + n16) * GST + quad * 16) =
                    make_float4(acc[0], acc[1], acc[2], acc[3]);
            }
#pragma unroll
            for (int it = 0; it < 4; ++it) {
                int row = it * 16 + (lane >> 2);
                uint4 v = *(const uint4*)(wst + row * GST + (lane & 3) * 16);
                int nd = r0 + row;
                if (nd < nrows)
                    *(uint4*)(NB + (size_t)nd * 1024 + 768 + qtr * 64 + (lane & 3) * 16) = v;
            }
        }
#pragma unroll
        for (int g = 0; g < 4; ++g) { a0[g] = b0[g]; a1[g] = b1[g]; }
    }
}

// ---------------- Attention: split-wave edge pairs, int8 dot ---------------
__global__ __launch_bounds__(256) void k_attn(
    const unsigned char* __restrict__ NB,
    const int* __restrict__ offs, const int* __restrict__ bsums,
    const int* __restrict__ csr_src,
    float* __restrict__ out, unsigned short* __restrict__ Xb,
    int n, int Etot, int mode)
{
    int node = blockIdx.x * 4 + (threadIdx.x >> 6);
    if (node >= n) return;
    int lane = threadIdx.x & 63;
    int sl = lane & 31;
    int half = lane >> 5;
    uint2 q8 = *(const uint2*)(NB + (size_t)node * 1024 + sl * 8);
    int beg = offs[node] + bsums[node >> 11];
    int end = (node + 1 < n) ? (offs[node + 1] + bsums[(node + 1) >> 11]) : Etot;
    float l = 0.f;
    float acc[8];
#pragma unroll
    for (int i = 0; i < 8; ++i) acc[i] = 0.f;
    for (int base = beg; base < end; base += 8) {
        int cnt = end - base; if (cnt > 8) cnt = 8;
        int my = (lane < cnt) ? csr_src[base + lane] : 0;
        uint2 kk[4], vv[4];
#pragma unroll
        for (int p = 0; p < 4; ++p) {
            int idx = __shfl(my, 2 * p + half);
            const unsigned char* row = NB + (size_t)idx * 1024 + 256 + sl * 8;
            kk[p] = *(const uint2*)(row);
            vv[p] = *(const uint2*)(row + 256);
        }
#pragma unroll
        for (int p = 0; p < 4; ++p) {
            int d = sdot4(kk[p].x, q8.x, 0);
            d = sdot4(kk[p].y, q8.y, d);
            d += __shfl_xor(d, 1); d += __shfl_xor(d, 2); d += __shfl_xor(d, 4);
            float w = __builtin_exp2f((float)d * C_EXP2);
            w = (2 * p + half < cnt) ? w : 0.f;
            l += w;
            float4 va = fp8x4_unpack(vv[p].x);
            float4 vb = fp8x4_unpack(vv[p].y);
            acc[0] += va.x * w; acc[1] += va.y * w;
            acc[2] += va.z * w; acc[3] += va.w * w;
            acc[4] += vb.x * w; acc[5] += vb.y * w;
            acc[6] += vb.z * w; acc[7] += vb.w * w;
        }
    }
    l += __shfl_xor(l, 32);
#pragma unroll
    for (int i = 0; i < 8; ++i) acc[i] += __shfl_xor(acc[i], 32);
    float inv = 1.f / (l + 1e-16f);
#pragma unroll
    for (int i = 0; i < 8; ++i) acc[i] *= inv;
#pragma unroll
    for (int i = 0; i < 8; ++i) {
        acc[i] += __shfl_xor(acc[i], 8);
        acc[i] += __shfl_xor(acc[i], 16);
        acc[i] *= 0.25f;
    }
    if (lane < 8) {
        const float* Srow = (const float*)(NB + (size_t)node * 1024 + 768);
        float4 s0 = *(const float4*)(Srow + lane * 8);
        float4 s1 = *(const float4*)(Srow + lane * 8 + 4);
        float r0 = acc[0] + s0.x, r1 = acc[1] + s0.y;
        float r2 = acc[2] + s0.z, r3 = acc[3] + s0.w;
        float r4 = acc[4] + s1.x, r5 = acc[5] + s1.y;
        float r6 = acc[6] + s1.z, r7 = acc[7] + s1.w;
        if (mode == 1) {
            r0 = fmaxf(r0, 0.f); r1 = fmaxf(r1, 0.f);
            r2 = fmaxf(r2, 0.f); r3 = fmaxf(r3, 0.f);
            r4 = fmaxf(r4, 0.f); r5 = fmaxf(r5, 0.f);
            r6 = fmaxf(r6, 0.f); r7 = fmaxf(r7, 0.f);
            uint4 o;
            o.x = (unsigned int)f2bf(r0) | ((unsigned int)f2bf(r1) << 16);
            o.y = (unsigned int)f2bf(r2) | ((unsigned int)f2bf(r3) << 16);
            o.z = (unsigned int)f2bf(r4) | ((unsigned int)f2bf(r5) << 16);
            o.w = (unsigned int)f2bf(r6) | ((unsigned int)f2bf(r7) << 16);
            *(uint4*)(Xb + (size_t)node * 64 + lane * 8) = o;
        } else {
            *(float4*)(out + (size_t)node * 64 + lane * 8) = make_float4(r0, r1, r2, r3);
            *(float4*)(out + (size_t)node * 64 + lane * 8 + 4) = make_float4(r4, r5, r6, r7);
        }
    }
}

extern "C" void kernel_launch(void* const* d_in, const int* in_sizes, int n_in,
                              void* d_out, int out_size, void* d_ws, size_t ws_size,
                              hipStream_t stream)
{
    const float* x  = (const float*)d_in[0];
    const int*   ei = (const int*)d_in[1];
    int N = in_sizes[0] / 64;
    int E = in_sizes[1] / 2;
    const int* srcp = ei;
    const int* dstp = ei + E;
    const float* Wq1 = (const float*)d_in[2],  *bq1 = (const float*)d_in[3];
    const float* Wk1 = (const float*)d_in[4],  *bk1 = (const float*)d_in[5];
    const float* Wv1 = (const float*)d_in[6],  *bv1 = (const float*)d_in[7];
    const float* Ws1 = (const float*)d_in[8],  *bs1 = (const float*)d_in[9];
    const float* Wq2 = (const float*)d_in[10], *bq2 = (const float*)d_in[11];
    const float* Wk2 = (const float*)d_in[12], *bk2 = (const float*)d_in[13];
    const float* Wv2 = (const float*)d_in[14], *bv2 = (const float*)d_in[15];
    const float* Ws2 = (const float*)d_in[16], *bs2 = (const float*)d_in[17];
    float* out = (float*)d_out;

    // workspace layout (~125 MB)
    char* ws = (char*)d_ws;
    size_t off = 0;
    auto alloc = [&](size_t bytes) -> void* {
        void* p = ws + off;
        off = (off + bytes + 255) & ~(size_t)255;
        return p;
    };
    unsigned short* Xb = (unsigned short*)alloc((size_t)N * 64 * 2);
    unsigned char* NB  = (unsigned char*)alloc(((size_t)N + 64) * 1024);
    unsigned short* Wt = (unsigned short*)alloc(2 * 53248 * 2);
    int* counts = (int*)alloc((size_t)N * 4);
    int* rank   = (int*)alloc((size_t)E * 4);
    int* offs   = (int*)alloc((size_t)N * 4);
    int* bsums  = (int*)alloc(1024 * 4);
    int* csr    = (int*)alloc((size_t)E * 4);
    (void)n_in; (void)out_size;
    if (off > ws_size) return;  // diagnostic: too-small ws -> zeros, not a fault

    int ebl = (E + 255) / 256;
    int nb_scan = (N + SCAN_CHUNK - 1) / SCAN_CHUNK;
    int ntiles = (N + 63) / 64;
    int gemm_bl = ntiles < 512 ? ntiles : 512;   // persistent: ~3 tiles/block
    int hist_bl = (E + 255) / 256;
    int attn_bl = (N + 3) / 4;
    int ncast4 = N * 16;
    int castBl = (ncast4 + 255) / 256;
    int zeroBl = (N + 255) / 256;

    // 1. setup: cast X, prep weights, zero counts
    k_setup<<<castBl + 416 + zeroBl, 256, 0, stream>>>(
        x, Xb, ncast4, Wq1, Wk1, Wv1, Ws1, Wq2, Wk2, Wv2, Ws2, Wt, counts, N, castBl);

    // 2. layer-1 GEMM + fused hist (independent block ranges)
    k_gemm<<<gemm_bl + hist_bl, 256, 0, stream>>>(
        Xb, N, Wt, bq1, bk1, bv1, bs1, NB,
        dstp, E, counts, rank, gemm_bl, ntiles);

    // 3-5. CSR: scan, scan2, atomic-free scatter
    k_scan1<<<nb_scan, SCAN_B, 0, stream>>>(counts, N, offs, bsums);
    k_scan2<<<1, 256, 0, stream>>>(bsums, nb_scan);
    k_scatter<<<ebl, 256, 0, stream>>>(srcp, dstp, E, offs, bsums, rank, csr);

    // 6. layer-1 attention (h1 -> Xb bf16)
    k_attn<<<attn_bl, 256, 0, stream>>>(NB, offs, bsums, csr, out, Xb, N, E, 1);

    // 7. layer-2 GEMM (no hist blocks)
    k_gemm<<<gemm_bl, 256, 0, stream>>>(
        Xb, N, Wt + 53248, bq2, bk2, bv2, bs2, NB,
        dstp, 0, counts, rank, gemm_bl, ntiles);

    // 8. layer-2 attention
    k_attn<<<attn_bl, 256, 0, stream>>>(NB, offs, bsums, csr, out, Xb, N, E, 0);
}

// Round 6
// 362.268 us; speedup vs baseline: 1.3261x; 1.0120x over previous
//
#include <hip/hip_runtime.h>
#include <hip/hip_fp16.h>
#include <math.h>

// Graph TransformerConv ×2 on MI355X. N=100k, E=800k, D=64, H=4, C=64.
//
// R19: attack k_attn (now the bottleneck: 2x78us, VALUBusy 81%).
//  - Packed PV accumulate: cvt_pk_f32_fp8 (f32x2) feeds v_pk_fma_f32
//    (__builtin_elementwise_fma on f32x2): 8 v_fmac -> 4 pk_fma per edge.
//  - SoA planes replace NB[node][1024]: Qp/Kp/Vp (256 B/node, i8/i8/fp8)
//    + Sp (256 B/node f32). Attn gather = one 32-bit lshl_add offset
//    (saddr form), same offset reused for K and V planes.
//  - Depth-1 csr_src prefetch kills the serial load->shfl chain at each
//    8-edge iteration head.
//  - k_gemm: R18 persistent-weight structure unchanged; flush now writes
//    64-B segments at stride 256 (4-KB span/inst, dense channel cycling)
//    instead of stride 1024 (16-KB span).
// CSR: hist stores rank[e] (one atomic pass, fused into layer-1 GEMM
// dispatch); scatter atomic-free. 8 dispatches. Workspace ~125 MB.

typedef __attribute__((ext_vector_type(8))) short bf16x8;
typedef __attribute__((ext_vector_type(4))) float f32x4;
typedef __attribute__((ext_vector_type(2))) float f32x2;

#define QKSCALE 32.0f
#define C_EXP2 1.760325e-4f   // log2e / (32*32*8)

__device__ inline unsigned short f2bf(float f) {
    unsigned int u = __float_as_uint(f);
    u = (u + 0x7fffu + ((u >> 16) & 1u)) >> 16;
    return (unsigned short)u;
}

#if __has_builtin(__builtin_amdgcn_cvt_pk_fp8_f32) && __has_builtin(__builtin_amdgcn_cvt_pk_f32_fp8)
#define HW_FP8 1
#endif

#ifndef HW_FP8
__device__ inline unsigned int fp8_enc1(float f) {
    unsigned int u = __float_as_uint(f);
    unsigned int s = (u >> 24) & 0x80u;
    float a = fabsf(f);
    if (a >= 448.f) return s | 0x7Eu;
    if (a < 0.015625f) return s;
    unsigned int ua = __float_as_uint(a);
    unsigned int r = ua + 0x7FFFFu + ((ua >> 20) & 1u);
    int e = (int)((r >> 23) & 255u) - 120;
    unsigned int m = (r >> 20) & 7u;
    if (e < 1) return s;
    if (e > 15) return s | 0x7Eu;
    return s | (unsigned int)((e << 3) | m);
}
__device__ inline float fp8_dec1(unsigned int b) {
    unsigned int e = (b >> 3) & 15u, m = b & 7u;
    float v;
    if (e) v = __uint_as_float(((e + 120u) << 23) | (m << 20));
    else   v = (float)m * 0.001953125f;
    return (b & 0x80u) ? -v : v;
}
#endif

__device__ inline unsigned int fp8x4_pack(float f0, float f1, float f2, float f3) {
#ifdef HW_FP8
    int pk = __builtin_amdgcn_cvt_pk_fp8_f32(f0, f1, 0, false);
    pk = __builtin_amdgcn_cvt_pk_fp8_f32(f2, f3, pk, true);
    return (unsigned int)pk;
#else
    return fp8_enc1(f0) | (fp8_enc1(f1) << 8) | (fp8_enc1(f2) << 16) | (fp8_enc1(f3) << 24);
#endif
}

__device__ inline unsigned int i8x4_pack(float f0, float f1, float f2, float f3) {
    int a = (int)rintf(f0 * QKSCALE); a = a < -127 ? -127 : (a > 127 ? 127 : a);
    int b = (int)rintf(f1 * QKSCALE); b = b < -127 ? -127 : (b > 127 ? 127 : b);
    int c = (int)rintf(f2 * QKSCALE); c = c < -127 ? -127 : (c > 127 ? 127 : c);
    int d = (int)rintf(f3 * QKSCALE); d = d < -127 ? -127 : (d > 127 ? 127 : d);
    return (unsigned int)((a & 255) | ((b & 255) << 8) | ((c & 255) << 16) | ((d & 255) << 24));
}

__device__ inline int sdot4(unsigned int a, unsigned int b, int c) {
#if __has_builtin(__builtin_amdgcn_sdot4)
    return __builtin_amdgcn_sdot4((int)a, (int)b, c, false);
#else
    int r = c;
#pragma unroll
    for (int i = 0; i < 4; ++i) {
        int ai = (int)(a << (24 - 8 * i)) >> 24;
        int bi = (int)(b << (24 - 8 * i)) >> 24;
        r += ai * bi;
    }
    return r;
#endif
}

// ---------------- setup: X cast + weight prep (both layers) + CSR zero -----
__global__ void k_setup(
    const float* __restrict__ x, unsigned short* __restrict__ Xb, int ncast4,
    const float* __restrict__ Wq1, const float* __restrict__ Wk1,
    const float* __restrict__ Wv1, const float* __restrict__ Ws1,
    const float* __restrict__ Wq2, const float* __restrict__ Wk2,
    const float* __restrict__ Wv2, const float* __restrict__ Ws2,
    unsigned short* __restrict__ Wt,
    int* __restrict__ counts, int N, int castBl)
{
    int b = blockIdx.x, tid = threadIdx.x;
    if (b < castBl) {
        int i = b * 256 + tid;
        if (i < ncast4) {
            float4 v = ((const float4*)x)[i];
            ushort4 o;
            o.x = f2bf(v.x); o.y = f2bf(v.y); o.z = f2bf(v.z); o.w = f2bf(v.w);
            ((ushort4*)Xb)[i] = o;
        }
    } else if (b < castBl + 416) {
        int j = (b - castBl) * 256 + tid;   // < 106496
        int layer = j / 53248;
        int r = j % 53248;
        if (r < 49152) {
            int m = r / 16384, w = r % 16384;
            int n = w / 64, k = w % 64;
            const float* W = (layer == 0)
                ? ((m == 0) ? Wq1 : (m == 1) ? Wk1 : Wv1)
                : ((m == 0) ? Wq2 : (m == 1) ? Wk2 : Wv2);
            Wt[layer * 53248 + m * 16384 + n * 64 + k] = f2bf(W[k * 256 + n]);
        } else {
            int w = r - 49152;
            int n = w / 64, k = w % 64;
            const float* W = (layer == 0) ? Ws1 : Ws2;
            Wt[layer * 53248 + 49152 + n * 64 + k] = f2bf(W[k * 64 + n]);
        }
    } else {
        int i = (b - castBl - 416) * 256 + tid;
        if (i < N) counts[i] = 0;
    }
}

// ---------------- CSR scan ----------------
#define SCAN_B 256
#define SCAN_CHUNK 2048
__global__ void k_scan1(const int* __restrict__ counts, int n,
                        int* __restrict__ offs, int* __restrict__ bsums) {
    __shared__ int lds[SCAN_B];
    int b = blockIdx.x, tid = threadIdx.x;
    int base = b * SCAN_CHUNK + tid * 8;
    int v[8]; int s = 0;
#pragma unroll
    for (int i = 0; i < 8; ++i) { int idx = base + i; int c = (idx < n) ? counts[idx] : 0; v[i] = s; s += c; }
    lds[tid] = s;
    for (int off = 1; off < SCAN_B; off <<= 1) {
        __syncthreads();
        int x = (tid >= off) ? lds[tid - off] : 0;
        __syncthreads();
        lds[tid] += x;
    }
    __syncthreads();
    int texcl = lds[tid] - s;
#pragma unroll
    for (int i = 0; i < 8; ++i) { int idx = base + i; if (idx < n) offs[idx] = texcl + v[i]; }
    if (tid == SCAN_B - 1) bsums[b] = lds[tid];
}

__global__ void k_scan2(int* bsums, int nb) {
    __shared__ int lds[256];
    int t = threadIdx.x;
    if (nb > 256) {
        if (t == 0) { int s = 0; for (int i = 0; i < nb; ++i) { int c = bsums[i]; bsums[i] = s; s += c; } }
        return;
    }
    int v = (t < nb) ? bsums[t] : 0;
    lds[t] = v;
    for (int off = 1; off < 256; off <<= 1) {
        __syncthreads();
        int x = (t >= off) ? lds[t - off] : 0;
        __syncthreads();
        lds[t] += x;
    }
    __syncthreads();
    if (t < nb) bsums[t] = lds[t] - v;   // exclusive
}

// atomic-free scatter using per-edge rank from the hist pass
__global__ void k_scatter(const int* __restrict__ src, const int* __restrict__ dst, int E,
                          const int* __restrict__ offs, const int* __restrict__ bsums,
                          const int* __restrict__ rank, int* __restrict__ csr_src) {
    int e = blockIdx.x * 256 + threadIdx.x;
    if (e < E) {
        int d = dst[e];
        csr_src[offs[d] + bsums[d >> 11] + rank[e]] = src[e];
    }
}

// ---------------- persistent fused GEMM (+hist blocks) ---------------------
// 512 blocks x 256 thd. Wave w = ch-quarter w. Weights for the quarter
// (Q/K/V: 8 bf16x8 each, S: 2) live in registers for the whole kernel.
// Grid-stride loop over 64-node tiles: prefetch A(t+1) -> 104 MFMAs from
// registers (bias as C-in from LDS) -> pack -> wave-private LDS patch
// (64x68 B) -> 16 dwordx4 stores per mat into its SoA plane (64-B
// segments at stride 256 -> dense channel cycling). Zero barriers in loop.
#define GST 68
__global__ __launch_bounds__(256, 2) void k_gemm(
    const unsigned short* __restrict__ Xb, int nrows,
    const unsigned short* __restrict__ WtL,
    const float* __restrict__ bqp, const float* __restrict__ bkp,
    const float* __restrict__ bvp, const float* __restrict__ bsp,
    unsigned char* __restrict__ Qp, unsigned char* __restrict__ Kp,
    unsigned char* __restrict__ Vp, unsigned char* __restrict__ Sp,
    const int* __restrict__ dstp, int histE,
    int* __restrict__ counts, int* __restrict__ rank, int gemmBl, int ntiles)
{
    __shared__ unsigned char st[4][64 * GST];   // 17408 B
    __shared__ float bias[832];                 // Q@0 K@256 V@512 S@768
    int tid = threadIdx.x;
    if (blockIdx.x >= gemmBl) {                  // ---- hist blocks ----
        int e = (blockIdx.x - gemmBl) * 256 + tid;
        if (e < histE) rank[e] = atomicAdd(&counts[dstp[e]], 1);
        return;
    }
    int qtr = tid >> 6, lane = tid & 63;
    int quad = lane >> 4, n16 = lane & 15;
    unsigned char* wst = st[qtr];

    // stage biases once (832 floats = 208 float4)
    if (tid < 208) {
        float4 b4;
        if (tid < 64)       b4 = ((const float4*)bqp)[tid];
        else if (tid < 128) b4 = ((const float4*)bkp)[tid - 64];
        else if (tid < 192) b4 = ((const float4*)bvp)[tid - 128];
        else                b4 = ((const float4*)bsp)[tid - 192];
        ((float4*)bias)[tid] = b4;
    }

    // ---- weights for this wave's quarter -> registers (once) ----
    const unsigned short* Wq = WtL;
    const unsigned short* Wk = WtL + 16384;
    const unsigned short* Wv = WtL + 32768;
    const unsigned short* Ws = WtL + 49152;
    bf16x8 fQ[8], fK[8], fV[8], fS[2];
#pragma unroll
    for (int c = 0; c < 4; ++c) {
        int roff = ((qtr * 4 + c) * 16 + n16) * 64 + quad * 8;
        fQ[2 * c]     = *(const bf16x8*)(Wq + roff);
        fQ[2 * c + 1] = *(const bf16x8*)(Wq + roff + 32);
        fK[2 * c]     = *(const bf16x8*)(Wk + roff);
        fK[2 * c + 1] = *(const bf16x8*)(Wk + roff + 32);
        fV[2 * c]     = *(const bf16x8*)(Wv + roff);
        fV[2 * c + 1] = *(const bf16x8*)(Wv + roff + 32);
    }
    {
        int roff = (qtr * 16 + n16) * 64 + quad * 8;
        fS[0] = *(const bf16x8*)(Ws + roff);
        fS[1] = *(const bf16x8*)(Ws + roff + 32);
    }
    __syncthreads();   // bias visibility (one-time drain, amortized)

    auto loadA = [&](int t, bf16x8 (&x0)[4], bf16x8 (&x1)[4]) {
        int r0 = t * 64;
#pragma unroll
        for (int g = 0; g < 4; ++g) {
            int node = r0 + g * 16 + n16;
            int nodec = (node < nrows) ? node : (nrows - 1);
            x0[g] = *(const bf16x8*)(Xb + (size_t)nodec * 64 + quad * 8);
            x1[g] = *(const bf16x8*)(Xb + (size_t)nodec * 64 + 32 + quad * 8);
        }
    };

    // one mat: 4 ctiles x 4 node groups, bias as C-in; then dense flush
    auto do_mat = [&](const bf16x8 (&fm)[8], int boff, unsigned char* plane,
                      bool isInt8, int r0,
                      const bf16x8 (&x0)[4], const bf16x8 (&x1)[4]) {
#pragma unroll
        for (int c = 0; c < 4; ++c) {
            float4 cb = *(const float4*)(bias + boff + qtr * 64 + c * 16 + quad * 4);
#pragma unroll
            for (int g = 0; g < 4; ++g) {
                f32x4 acc = {cb.x, cb.y, cb.z, cb.w};
                acc = __builtin_amdgcn_mfma_f32_16x16x32_bf16(fm[2 * c],     x0[g], acc, 0, 0, 0);
                acc = __builtin_amdgcn_mfma_f32_16x16x32_bf16(fm[2 * c + 1], x1[g], acc, 0, 0, 0);
                unsigned int pk = isInt8 ? i8x4_pack(acc[0], acc[1], acc[2], acc[3])
                                         : fp8x4_pack(acc[0], acc[1], acc[2], acc[3]);
                *(unsigned int*)(wst + (g * 16 + n16) * GST + c * 16 + quad * 4) = pk;
            }
        }
#pragma unroll
        for (int it = 0; it < 4; ++it) {
            int row = it * 16 + (lane >> 2);
            uint4 v = *(const uint4*)(wst + row * GST + (lane & 3) * 16);
            int nd = r0 + row;
            if (nd < nrows)
                *(uint4*)(plane + (size_t)nd * 256 + qtr * 64 + (lane & 3) * 16) = v;
        }
    };

    // ---- grid-stride tile loop with depth-1 A prefetch ----
    bf16x8 a0[4], a1[4], b0[4], b1[4];
    int t = blockIdx.x;
    if (t < ntiles) loadA(t, a0, a1);
    for (; t < ntiles; t += gemmBl) {
        int tn = t + gemmBl;
        if (tn < ntiles) loadA(tn, b0, b1);
        int r0 = t * 64;
        do_mat(fQ, 0,   Qp, true,  r0, a0, a1);   // Q int8
        do_mat(fK, 256, Kp, true,  r0, a0, a1);   // K int8
        do_mat(fV, 512, Vp, false, r0, a0, a1);   // V fp8
        // S (fp32 skip): quarter = 16 ch, bias as C-in, direct f32 patch
        {
            float4 cs = *(const float4*)(bias + 768 + qtr * 16 + quad * 4);
#pragma unroll
            for (int g = 0; g < 4; ++g) {
                f32x4 acc = {cs.x, cs.y, cs.z, cs.w};
                acc = __builtin_amdgcn_mfma_f32_16x16x32_bf16(fS[0], a0[g], acc, 0, 0, 0);
                acc = __builtin_amdgcn_mfma_f32_16x16x32_bf16(fS[1], a1[g], acc, 0, 0, 0);
                *(float4*)(wst + (g * 16 + n16) * GST + quad * 16) =
                    make_float4(acc[0], acc[1], acc[2], acc[3]);
            }
#pragma unroll
            for (int it = 0; it < 4; ++it) {
                int row = it * 16 + (lane >> 2);
                uint4 v = *(const uint4*)(wst + row * GST + (lane & 3) * 16);
                int nd = r0 + row;
                if (nd < nrows)
                    *(uint4*)(Sp + (size_t)nd * 256 + qtr * 64 + (lane & 3) * 16) = v;
            }
        }
#pragma unroll
        for (int g = 0; g < 4; ++g) { a0[g] = b0[g]; a1[g] = b1[g]; }
    }
}

// ---------------- Attention: split-wave edge pairs, int8 dot ---------------
// Wave = 1 node; 8 edges/iter (2 halves x 4). 32-bit saddr offsets into
// SoA planes; depth-1 csr prefetch; packed f32x2 PV accumulate (pk_fma).
__global__ __launch_bounds__(256) void k_attn(
    const unsigned char* __restrict__ Qp, const unsigned char* __restrict__ Kp,
    const unsigned char* __restrict__ Vp, const float* __restrict__ Sp,
    const int* __restrict__ offs, const int* __restrict__ bsums,
    const int* __restrict__ csr_src,
    float* __restrict__ out, unsigned short* __restrict__ Xb,
    int n, int Etot, int mode)
{
    int node = blockIdx.x * 4 + (threadIdx.x >> 6);
    if (node >= n) return;
    int lane = threadIdx.x & 63;
    int sl = lane & 31;
    int half = lane >> 5;
    unsigned slb = (unsigned)sl * 8u;
    uint2 q8 = *(const uint2*)(Qp + ((unsigned)node << 8) + slb);
    int beg = offs[node] + bsums[node >> 11];
    int end = (node + 1 < n) ? (offs[node + 1] + bsums[(node + 1) >> 11]) : Etot;
    float l = 0.f;
    f32x2 acc2[4];
#pragma unroll
    for (int i = 0; i < 4; ++i) acc2[i] = (f32x2){0.f, 0.f};
    int my = (beg + lane < end) ? csr_src[beg + lane] : 0;
    for (int base = beg; base < end; base += 8) {
        int myn = (base + 8 + lane < end) ? csr_src[base + 8 + lane] : 0;
        int cnt = end - base; if (cnt > 8) cnt = 8;
        uint2 kk[4], vv[4];
#pragma unroll
        for (int p = 0; p < 4; ++p) {
            int idx = __shfl(my, 2 * p + half);
            unsigned off = ((unsigned)idx << 8) + slb;
            kk[p] = *(const uint2*)(Kp + off);
            vv[p] = *(const uint2*)(Vp + off);
        }
#pragma unroll
        for (int p = 0; p < 4; ++p) {
            int d = sdot4(kk[p].x, q8.x, 0);
            d = sdot4(kk[p].y, q8.y, d);
            d += __shfl_xor(d, 1); d += __shfl_xor(d, 2); d += __shfl_xor(d, 4);
            float w = __builtin_exp2f((float)d * C_EXP2);
            w = (2 * p + half < cnt) ? w : 0.f;
            l += w;
            f32x2 w2 = {w, w};
#ifdef HW_FP8
            f32x2 va = __builtin_amdgcn_cvt_pk_f32_fp8((int)vv[p].x, false);
            f32x2 vb = __builtin_amdgcn_cvt_pk_f32_fp8((int)vv[p].x, true);
            f32x2 vc = __builtin_amdgcn_cvt_pk_f32_fp8((int)vv[p].y, false);
            f32x2 vd = __builtin_amdgcn_cvt_pk_f32_fp8((int)vv[p].y, true);
#else
            f32x2 va = {fp8_dec1(vv[p].x & 255u), fp8_dec1((vv[p].x >> 8) & 255u)};
            f32x2 vb = {fp8_dec1((vv[p].x >> 16) & 255u), fp8_dec1(vv[p].x >> 24)};
            f32x2 vc = {fp8_dec1(vv[p].y & 255u), fp8_dec1((vv[p].y >> 8) & 255u)};
            f32x2 vd = {fp8_dec1((vv[p].y >> 16) & 255u), fp8_dec1(vv[p].y >> 24)};
#endif
            acc2[0] = __builtin_elementwise_fma(va, w2, acc2[0]);
            acc2[1] = __builtin_elementwise_fma(vb, w2, acc2[1]);
            acc2[2] = __builtin_elementwise_fma(vc, w2, acc2[2]);
            acc2[3] = __builtin_elementwise_fma(vd, w2, acc2[3]);
        }
        my = myn;
    }
    float acc[8] = {acc2[0][0], acc2[0][1], acc2[1][0], acc2[1][1],
                    acc2[2][0], acc2[2][1], acc2[3][0], acc2[3][1]};
    l += __shfl_xor(l, 32);
#pragma unroll
    for (int i = 0; i < 8; ++i) acc[i] += __shfl_xor(acc[i], 32);
    float inv = 1.f / (l + 1e-16f);
#pragma unroll
    for (int i = 0; i < 8; ++i) acc[i] *= inv;
#pragma unroll
    for (int i = 0; i < 8; ++i) {
        acc[i] += __shfl_xor(acc[i], 8);
        acc[i] += __shfl_xor(acc[i], 16);
        acc[i] *= 0.25f;
    }
    if (lane < 8) {
        const float* Srow = Sp + ((size_t)node << 6);
        float4 s0 = *(const float4*)(Srow + lane * 8);
        float4 s1 = *(const float4*)(Srow + lane * 8 + 4);
        float r0 = acc[0] + s0.x, r1 = acc[1] + s0.y;
        float r2 = acc[2] + s0.z, r3 = acc[3] + s0.w;
        float r4 = acc[4] + s1.x, r5 = acc[5] + s1.y;
        float r6 = acc[6] + s1.z, r7 = acc[7] + s1.w;
        if (mode == 1) {
            r0 = fmaxf(r0, 0.f); r1 = fmaxf(r1, 0.f);
            r2 = fmaxf(r2, 0.f); r3 = fmaxf(r3, 0.f);
            r4 = fmaxf(r4, 0.f); r5 = fmaxf(r5, 0.f);
            r6 = fmaxf(r6, 0.f); r7 = fmaxf(r7, 0.f);
            uint4 o;
            o.x = (unsigned int)f2bf(r0) | ((unsigned int)f2bf(r1) << 16);
            o.y = (unsigned int)f2bf(r2) | ((unsigned int)f2bf(r3) << 16);
            o.z = (unsigned int)f2bf(r4) | ((unsigned int)f2bf(r5) << 16);
            o.w = (unsigned int)f2bf(r6) | ((unsigned int)f2bf(r7) << 16);
            *(uint4*)(Xb + (size_t)node * 64 + lane * 8) = o;
        } else {
            *(float4*)(out + (size_t)node * 64 + lane * 8) = make_float4(r0, r1, r2, r3);
            *(float4*)(out + (size_t)node * 64 + lane * 8 + 4) = make_float4(r4, r5, r6, r7);
        }
    }
}

extern "C" void kernel_launch(void* const* d_in, const int* in_sizes, int n_in,
                              void* d_out, int out_size, void* d_ws, size_t ws_size,
                              hipStream_t stream)
{
    const float* x  = (const float*)d_in[0];
    const int*   ei = (const int*)d_in[1];
    int N = in_sizes[0] / 64;
    int E = in_sizes[1] / 2;
    const int* srcp = ei;
    const int* dstp = ei + E;
    const float* Wq1 = (const float*)d_in[2],  *bq1 = (const float*)d_in[3];
    const float* Wk1 = (const float*)d_in[4],  *bk1 = (const float*)d_in[5];
    const float* Wv1 = (const float*)d_in[6],  *bv1 = (const float*)d_in[7];
    const float* Ws1 = (const float*)d_in[8],  *bs1 = (const float*)d_in[9];
    const float* Wq2 = (const float*)d_in[10], *bq2 = (const float*)d_in[11];
    const float* Wk2 = (const float*)d_in[12], *bk2 = (const float*)d_in[13];
    const float* Wv2 = (const float*)d_in[14], *bv2 = (const float*)d_in[15];
    const float* Ws2 = (const float*)d_in[16], *bs2 = (const float*)d_in[17];
    float* out = (float*)d_out;

    // workspace layout (~125 MB)
    char* ws = (char*)d_ws;
    size_t off = 0;
    auto alloc = [&](size_t bytes) -> void* {
        void* p = ws + off;
        off = (off + bytes + 255) & ~(size_t)255;
        return p;
    };
    unsigned short* Xb = (unsigned short*)alloc((size_t)N * 64 * 2);
    unsigned char* Qp  = (unsigned char*)alloc(((size_t)N + 64) * 256);
    unsigned char* Kp  = (unsigned char*)alloc(((size_t)N + 64) * 256);
    unsigned char* Vp  = (unsigned char*)alloc(((size_t)N + 64) * 256);
    unsigned char* Sp  = (unsigned char*)alloc(((size_t)N + 64) * 256);
    unsigned short* Wt = (unsigned short*)alloc(2 * 53248 * 2);
    int* counts = (int*)alloc((size_t)N * 4);
    int* rank   = (int*)alloc((size_t)E * 4);
    int* offs   = (int*)alloc((size_t)N * 4);
    int* bsums  = (int*)alloc(1024 * 4);
    int* csr    = (int*)alloc((size_t)E * 4);
    (void)n_in; (void)out_size;
    if (off > ws_size) return;  // diagnostic: too-small ws -> zeros, not a fault

    int ebl = (E + 255) / 256;
    int nb_scan = (N + SCAN_CHUNK - 1) / SCAN_CHUNK;
    int ntiles = (N + 63) / 64;
    int gemm_bl = ntiles < 512 ? ntiles : 512;   // persistent: ~3 tiles/block
    int hist_bl = (E + 255) / 256;
    int attn_bl = (N + 3) / 4;
    int ncast4 = N * 16;
    int castBl = (ncast4 + 255) / 256;
    int zeroBl = (N + 255) / 256;

    // 1. setup: cast X, prep weights, zero counts
    k_setup<<<castBl + 416 + zeroBl, 256, 0, stream>>>(
        x, Xb, ncast4, Wq1, Wk1, Wv1, Ws1, Wq2, Wk2, Wv2, Ws2, Wt, counts, N, castBl);

    // 2. layer-1 GEMM + fused hist (independent block ranges)
    k_gemm<<<gemm_bl + hist_bl, 256, 0, stream>>>(
        Xb, N, Wt, bq1, bk1, bv1, bs1, Qp, Kp, Vp, Sp,
        dstp, E, counts, rank, gemm_bl, ntiles);

    // 3-5. CSR: scan, scan2, atomic-free scatter
    k_scan1<<<nb_scan, SCAN_B, 0, stream>>>(counts, N, offs, bsums);
    k_scan2<<<1, 256, 0, stream>>>(bsums, nb_scan);
    k_scatter<<<ebl, 256, 0, stream>>>(srcp, dstp, E, offs, bsums, rank, csr);

    // 6. layer-1 attention (h1 -> Xb bf16)
    k_attn<<<attn_bl, 256, 0, stream>>>(Qp, Kp, Vp, (const float*)Sp,
                                        offs, bsums, csr, out, Xb, N, E, 1);

    // 7. layer-2 GEMM (no hist blocks)
    k_gemm<<<gemm_bl, 256, 0, stream>>>(
        Xb, N, Wt + 53248, bq2, bk2, bv2, bs2, Qp, Kp, Vp, Sp,
        dstp, 0, counts, rank, gemm_bl, ntiles);

    // 8. layer-2 attention
    k_attn<<<attn_bl, 256, 0, stream>>>(Qp, Kp, Vp, (const float*)Sp,
                                        offs, bsums, csr, out, Xb, N, E, 0);
}